// Round 3
// 421.547 us; speedup vs baseline: 1.0626x; 1.0626x over previous
//
#include <hip/hip_runtime.h>

// ============================================================================
// GQA prefill: B=4, S=2048, DIM=1152, NH=8, KVH=2, HD=144, causal, start_pos=0
//
// R10 = R7 attention math EXACTLY, with 2x K/V staging amortization via
// HEAD-PAIR sharing instead of TQ=128 (R8/R9's TQ=128 row-remap bundle failed
// absmax 0.10/0.50 twice; bug not found by audit -> bisect from R7 baseline).
//  - Block (x, hp, b): 512 threads, 8 waves. Waves 0-3 -> head hp*2,
//    waves 4-7 -> head hp*2+1 (same kvh = hp>>1, block-uniform) sharing ONE
//    staged K/V tile. Per-wave compute is BYTE-IDENTICAL to R7: TQ=64 strip
//    (w4 = w&3), nkt = 2qi+2, band = kt >= nkt-2, unconditional rescale.
//  - grid (32,4,4) = 512 blocks -> 2 blocks/CU, 16 waves/CU. LDS 28672 B.
//  - Staging split over 8 waves (c = w; c < 18; c += 8): K chunks 0-8 and
//    V chunks 0-8 each staged exactly once (coverage verified).
//  - qi maps per b: {x, (x+16)&31, 31-x, (15-x)&31} -> CU-resident pairs
//    (i, i+256) = (b, b+2) have qi1+qi2 = 31 -> uniform 66 tiles/CU.
//
// R7 (unchanged): K and Vt pre-swizzled into MFMA-granule order:
//      Ksw granule = (tile*576 + (d>>3)*32 + (s&31)), elem d&7
//      Vsw granule = (tile*576 + ((s&31)>>3)*144 + d), elem s&7
//    -> attention staging = 18 contiguous 1KB global_load_lds per 32-key tile.
//
// ws layout (bytes):
//   x_sw     :         0 ..  18874368   (8192x1152 f16 swizzled, KC=144)
//   wqkv_sw  :  18874368 ..  23003136   (1792x1152 sw; rows>=1728 pad)
//   wo_sw    :  23003136 ..  25657344
//   bias_qkv :  25657344 ..  25664256
//   qkv f32  :  25664256 ..  82287360   (8192x1728 plain)
//   Qh       :  82287360 .. 101161728   (4,8,2048,144) f16 plain
//   Ksw      : 101161728 .. 105880320   (4,2) x 64 tiles x 576 granules
//   Vsw      : 105880320 .. 110598912   (4,2) x 64 tiles x 576 granules
//   attn_sw  : 110598912 .. 129473280   (8192x1152 f16 swizzled)
// ============================================================================

#define THREADS 256

typedef _Float16 f16x8 __attribute__((ext_vector_type(8)));
typedef _Float16 f16x4 __attribute__((ext_vector_type(4)));
typedef _Float16 f16x2 __attribute__((ext_vector_type(2)));
typedef float f32x4 __attribute__((ext_vector_type(4)));

// 16B global->LDS DMA: LDS dst = wave-uniform base + lane*16
#define GLDS16(gp, lp)                                                  \
  __builtin_amdgcn_global_load_lds(                                     \
      (const __attribute__((address_space(1))) unsigned int*)(gp),      \
      (__attribute__((address_space(3))) unsigned int*)(lp), 16, 0, 0)

// ---------------------------------------------------------------- cvt -> swizzled
// Identity thread->granule map (writes perfectly coalesced 16B/thread).
// nG = ceil(nrows/128)*128*KC; reads for R >= nrows clamp to nrows-1 (the
// corresponding granules are pad rows, discarded downstream).
__global__ __launch_bounds__(THREADS) void cvt_sw(const float* __restrict__ in,
                                                  _Float16* __restrict__ out,
                                                  int nG, int KC, int nrows) {
  int i = blockIdx.x * THREADS + threadIdx.x;
  if (i >= nG) return;
  int rr = i & 127;
  int j = i >> 7;
  int kc = j % KC;
  int rb = j / KC;
  int R = rb * 128 + rr;
  if (R >= nrows) R = nrows - 1;
  const float* src = in + (size_t)R * (KC * 8) + kc * 8;
  float4 a = *(const float4*)src;
  float4 c = *(const float4*)(src + 4);
  f16x8 o;
  o[0] = (_Float16)a.x; o[1] = (_Float16)a.y;
  o[2] = (_Float16)a.z; o[3] = (_Float16)a.w;
  o[4] = (_Float16)c.x; o[5] = (_Float16)c.y;
  o[6] = (_Float16)c.z; o[7] = (_Float16)c.w;
  *(f16x8*)(out + (size_t)i * 8) = o;
}

// ---------------------------------------------------------------- bias concat
__global__ __launch_bounds__(THREADS) void prep_bias(const float* __restrict__ bq,
                                                     const float* __restrict__ bkv,
                                                     float* __restrict__ bias) {
  int i = blockIdx.x * THREADS + threadIdx.x;
  if (i < 1152) bias[i] = bq[i];
  else if (i < 1728) bias[i] = bkv[i - 1152];
}

// ---------------------------------------------------------------- GEMM (swizzled)
// C[m,n] = sum_k A[m,k]*B[n,k] + bias[n]. A,B swizzled-granule f16; C f32 plain.
// 128x128 tile, BK=64, 4 waves; contiguous 1KB global_load_lds staging.
__global__ __launch_bounds__(THREADS) void gemm_sw(
    const _Float16* __restrict__ A, const _Float16* __restrict__ B,
    const float* __restrict__ bias, float* __restrict__ C, int M, int N, int K) {
  __shared__ __align__(16) _Float16 As[1024 * 8];  // 8 kc x 128 rows granules
  __shared__ __align__(16) _Float16 Bs[1024 * 8];
  const int t = threadIdx.x;
  const int w = t >> 6, lane = t & 63;
  const int quad = lane >> 4, l16 = lane & 15;
  const int wm = (w & 1) << 6, wn = (w >> 1) << 6;
  const int KC = K >> 3;
  const int mb = blockIdx.y, nb = blockIdx.x;
  const int m0 = mb << 7, n0 = nb << 7;

  f32x4 acc[4][4] = {};

  for (int kcb = 0; kcb < KC; kcb += 8) {
    const size_t Ab = ((size_t)mb * KC + kcb) << 7;  // granule base
    const size_t Bb = ((size_t)nb * KC + kcb) << 7;
#pragma unroll
    for (int j = 0; j < 4; ++j) {
      const int ii = (w << 2) + j;  // 16 chunks of 64 granules
      GLDS16(A + ((Ab + (ii << 6) + lane) << 3), &As[(ii << 6) * 8]);
      GLDS16(B + ((Bb + (ii << 6) + lane) << 3), &Bs[(ii << 6) * 8]);
    }
    __syncthreads();
#pragma unroll
    for (int ks = 0; ks < 2; ++ks) {
      f16x8 af[4], bf[4];
#pragma unroll
      for (int mi = 0; mi < 4; ++mi)
        af[mi] = *(const f16x8*)&As[((((ks << 2) + quad) << 7) + wm + (mi << 4) + l16) * 8];
#pragma unroll
      for (int ni = 0; ni < 4; ++ni)
        bf[ni] = *(const f16x8*)&Bs[((((ks << 2) + quad) << 7) + wn + (ni << 4) + l16) * 8];
#pragma unroll
      for (int mi = 0; mi < 4; ++mi)
#pragma unroll
        for (int ni = 0; ni < 4; ++ni)
          acc[mi][ni] =
              __builtin_amdgcn_mfma_f32_16x16x32_f16(af[mi], bf[ni], acc[mi][ni], 0, 0, 0);
    }
    __syncthreads();
  }

#pragma unroll
  for (int mi = 0; mi < 4; ++mi) {
    const int row = m0 + wm + (mi << 4) + (quad << 2);
#pragma unroll
    for (int ni = 0; ni < 4; ++ni) {
      const int col = n0 + wn + (ni << 4) + l16;
      if (col < N) {
        const float bv = bias[col];
#pragma unroll
        for (int r = 0; r < 4; ++r)
          C[(size_t)(row + r) * N + col] = acc[mi][ni][r] + bv;
      }
    }
  }
}

// ---------------------------------------------------------------- RoPE
// Q -> plain (b,h,s,144) f16.  K -> swizzled granules:
//   granule = ((b*2+kvh)*64 + (s>>5))*576 + (d2>>2)*32 + (s&31), elem (d2&3)*2.
__global__ __launch_bounds__(THREADS) void rope_scatter_f16(
    const float* __restrict__ qkv, const float* __restrict__ fc,
    const float* __restrict__ fs, _Float16* __restrict__ Qh,
    _Float16* __restrict__ Ksw) {
  int idx = blockIdx.x * THREADS + threadIdx.x;
  int m = idx / 720;
  int c = idx - m * 720;
  int s = m & 2047, b = m >> 11;
  const float* row = qkv + (size_t)m * 1728;
  int h, d2;
  const float* src;
  _Float16* dst;
  if (c < 576) {
    h = c / 72;
    d2 = c - h * 72;
    src = row + h * 144 + 2 * d2;
    dst = Qh + ((size_t)(b * 8 + h) * 2048 + s) * 144 + 2 * d2;
  } else {
    int cc = c - 576;
    h = cc / 72;  // kvh
    d2 = cc - h * 72;
    src = row + 1152 + h * 144 + 2 * d2;
    size_t g = ((size_t)(b * 2 + h) * 64 + (s >> 5)) * 576 + (d2 >> 2) * 32 + (s & 31);
    dst = Ksw + g * 8 + (d2 & 3) * 2;
  }
  float2 v = *(const float2*)src;
  float cth = fc[s * 72 + d2], sth = fs[s * 72 + d2];
  f16x2 o;
  o.x = (_Float16)(v.x * cth - v.y * sth);
  o.y = (_Float16)(v.x * sth + v.y * cth);
  *(f16x2*)dst = o;
}

// ---------------------------------------------------------------- V -> swizzled
// Vsw granule = ((b*2+kvh)*64 + kt)*576 + cc*144 + d;  kt=s>>5, cc=(s&31)>>3.
__global__ __launch_bounds__(THREADS) void v_transpose(const float* __restrict__ qkv,
                                                       _Float16* __restrict__ Vsw) {
  __shared__ _Float16 tile[128 * 145];
  const int t = threadIdx.x;
  const int s0 = blockIdx.x * 128;
  const int kvh = blockIdx.y, b = blockIdx.z;
  const float* src = qkv + ((size_t)(b * 2048 + s0)) * 1728 + 1440 + kvh * 144;
#pragma unroll
  for (int i = 0; i < 18; ++i) {
    int c = t + i * 256;  // 128 rows x 36 float4
    int r = c / 36, cc = c - r * 36;
    float4 v = *(const float4*)(src + (size_t)r * 1728 + cc * 4);
    int base = r * 145 + cc * 4;
    tile[base + 0] = (_Float16)v.x;
    tile[base + 1] = (_Float16)v.y;
    tile[base + 2] = (_Float16)v.z;
    tile[base + 3] = (_Float16)v.w;
  }
  __syncthreads();
  const size_t tb = ((size_t)(b * 2 + kvh) * 64 + (s0 >> 5)) * 576;
#pragma unroll
  for (int i = 0; i < 9; ++i) {
    int c = t + i * 256;  // 2304 = 16 s-chunks x 144 d  (d fastest -> coalesced)
    int sc = c / 144, d = c - sc * 144;
    f16x8 o;
#pragma unroll
    for (int j = 0; j < 8; ++j) o[j] = tile[(sc * 8 + j) * 145 + d];
    size_t g = tb + (size_t)(sc >> 2) * 576 + (sc & 3) * 144 + d;
    *(f16x8*)(Vsw + g * 8) = o;
  }
}

// ---------------------------------------------------------------- MFMA flash attention
// Block (x, hp, b): 8 waves; waves 0-3 head hp*2, waves 4-7 head hp*2+1
// (shared K/V, kvh = hp>>1 block-uniform). Per-wave: R7-exact TQ=64 strip
// (w4 = w&3 rows w4*16..+15), TK=32, nkt = 2qi+2, band = kt >= nkt-2,
// unconditional rescale. Two-barrier single-buffer schedule (R7-proven).
// LDS = 9216*2 + 10240 = 28672 B; 2 blocks/CU, 16 waves/CU.
#define STAGE_TILE(kt)                                                     \
  do {                                                                     \
    const _Float16* Kt_ = Ksw + (tbase + (size_t)(kt)) * 4608;             \
    const _Float16* Vt_ = Vsw + (tbase + (size_t)(kt)) * 4608;             \
    for (int c = w; c < 18; c += 8) {                                      \
      if (c < 9)                                                           \
        GLDS16(Kt_ + ((c << 6) + lane) * 8, &Ks[(c << 6) * 8]);            \
      else                                                                 \
        GLDS16(Vt_ + (((c - 9) << 6) + lane) * 8,                          \
               &Vs[((c - 9) << 6) * 8]);                                   \
    }                                                                      \
  } while (0)

__global__ __launch_bounds__(512, 4) void attn_mfma(
    const _Float16* __restrict__ Qh, const _Float16* __restrict__ Ksw,
    const _Float16* __restrict__ Vsw, _Float16* __restrict__ Out) {
  __shared__ __align__(16) _Float16 Ks[576 * 8];  // [kc 0..17][key 0..31]
  __shared__ __align__(16) _Float16 Vs[576 * 8];  // [cc 0..3][d 0..143]
  __shared__ __align__(16) _Float16 Ps[128 * 40]; // 8 waves x 16 q x 32 keys
  const int t = threadIdx.x;
  const int w = t >> 6, lane = t & 63;
  const int w4 = w & 3;                 // row strip within the 64-q tile
  const int quad = lane >> 4, l16 = lane & 15;
  const int x = blockIdx.x, hp = blockIdx.y, b = blockIdx.z;
  const int h = hp * 2 + (w >> 2);      // per-wave head
  const int kvh = hp >> 1;              // block-uniform
  const int qi = (b == 0) ? x
               : (b == 1) ? ((x + 16) & 31)
               : (b == 2) ? (31 - x)
                          : ((15 - x) & 31);
  const int q0 = qi * 64;
  const int nkt = 2 * qi + 2;  // 32-key tiles covering keys <= q0+63
  const _Float16* Qg = Qh + ((size_t)(b * 8 + h) * 2048 + q0) * 144;
  const size_t tbase = (size_t)(b * 2 + kvh) * 64;

  // Q fragments: rows w4*16 + l16
  f16x8 qf[4];
  f16x4 qt4;
  {
    const _Float16* qp = Qg + (size_t)(w4 * 16 + l16) * 144;
#pragma unroll
    for (int ks = 0; ks < 4; ++ks) qf[ks] = *(const f16x8*)(qp + ks * 32 + quad * 8);
    qt4 = *(const f16x4*)(qp + 128 + quad * 4);
  }

  f32x4 Oacc[9] = {};
  float mrow[4] = {-3e38f, -3e38f, -3e38f, -3e38f};
  float lrow[4] = {0.f, 0.f, 0.f, 0.f};
  const float scale = 0.08333333333333333f;  // 1/sqrt(144)
  const int colb = (l16 & ~1);
  const int rsel = (lane & 1) << 1;

  for (int kt = 0; kt < nkt; ++kt) {
    STAGE_TILE(kt);
    __syncthreads();

    // ---- QK^T: 16 rows x 32 keys
    f32x4 sc[2] = {};
#pragma unroll
    for (int ks = 0; ks < 4; ++ks) {
#pragma unroll
      for (int ct = 0; ct < 2; ++ct) {
        f16x8 bfr = *(const f16x8*)&Ks[(((ks * 4 + quad) << 5) + ct * 16 + l16) * 8];
        sc[ct] = __builtin_amdgcn_mfma_f32_16x16x32_f16(qf[ks], bfr, sc[ct], 0, 0, 0);
      }
    }
#pragma unroll
    for (int ct = 0; ct < 2; ++ct) {  // k=128..143 tail (legacy 16x16x16)
      f16x4 bt = *(const f16x4*)&Ks[(((16 + (quad >> 1)) << 5) + ct * 16 + l16) * 8 +
                                    (quad & 1) * 4];
      sc[ct] = __builtin_amdgcn_mfma_f32_16x16x16f16(qt4, bt, sc[ct], 0, 0, 0);
    }

    // ---- online softmax (rows q0+w4*16+quad*4+r, cols kt*32+ct*16+l16)
    const bool band = (kt >= nkt - 2);
    const int rowb = q0 + w4 * 16 + quad * 4;
    float vv[2][4];
    float mx[4] = {-3e38f, -3e38f, -3e38f, -3e38f};
#pragma unroll
    for (int ct = 0; ct < 2; ++ct) {
      const int cb = kt * 32 + ct * 16 + l16;
#pragma unroll
      for (int r = 0; r < 4; ++r) {
        float v = sc[ct][r] * scale;
        if (band && cb > rowb + r) v -= 1e9f;
        vv[ct][r] = v;
        mx[r] = fmaxf(mx[r], v);
      }
    }
    float alv[4];
#pragma unroll
    for (int r = 0; r < 4; ++r) {
      float m = mx[r];
      m = fmaxf(m, __shfl_xor(m, 1));
      m = fmaxf(m, __shfl_xor(m, 2));
      m = fmaxf(m, __shfl_xor(m, 4));
      m = fmaxf(m, __shfl_xor(m, 8));
      float mn = fmaxf(mrow[r], m);
      alv[r] = __expf(mrow[r] - mn);
      mrow[r] = mn;
    }
    float rs[4] = {0.f, 0.f, 0.f, 0.f};
#pragma unroll
    for (int ct = 0; ct < 2; ++ct) {
      float p[4], q[4];
#pragma unroll
      for (int r = 0; r < 4; ++r) {
        p[r] = __expf(vv[ct][r] - mrow[r]);
        rs[r] += p[r];
      }
#pragma unroll
      for (int r = 0; r < 4; ++r) q[r] = __shfl_xor(p[r], 1);
#pragma unroll
      for (int k = 0; k < 2; ++k) {  // paired f16x2, conflict-free
        const int r = rsel + k;
        f16x2 pv;
        if (lane & 1) {
          pv.x = (_Float16)q[r];
          pv.y = (_Float16)p[r];
        } else {
          pv.x = (_Float16)p[r];
          pv.y = (_Float16)q[r];
        }
        *(f16x2*)&Ps[(w * 16 + quad * 4 + r) * 40 + ct * 16 + colb] = pv;
      }
    }
#pragma unroll
    for (int r = 0; r < 4; ++r) {
      float v = rs[r];
      v += __shfl_xor(v, 1);
      v += __shfl_xor(v, 2);
      v += __shfl_xor(v, 4);
      v += __shfl_xor(v, 8);
      lrow[r] = lrow[r] * alv[r] + v;
    }
#pragma unroll
    for (int nt = 0; nt < 9; ++nt)
#pragma unroll
      for (int r = 0; r < 4; ++r) Oacc[nt][r] *= alv[r];

    // ---- PV: O(16x144) += P(16x32) @ V(32x144); Ps strip wave-local
    {
      f16x8 pa = *(const f16x8*)&Ps[(w * 16 + l16) * 40 + quad * 8];
#pragma unroll
      for (int nt = 0; nt < 9; ++nt) {
        f16x8 vb = *(const f16x8*)&Vs[(quad * 144 + nt * 16 + l16) * 8];
        Oacc[nt] = __builtin_amdgcn_mfma_f32_16x16x32_f16(pa, vb, Oacc[nt], 0, 0, 0);
      }
    }
    __syncthreads();
  }

  // ---- epilogue: normalize, write swizzled-granule f16 (out-proj A input)
  float inv[4];
#pragma unroll
  for (int r = 0; r < 4; ++r) inv[r] = 1.f / lrow[r];
#pragma unroll
  for (int nt = 0; nt < 9; ++nt) {
    float o[4], qn[4];
#pragma unroll
    for (int r = 0; r < 4; ++r) o[r] = Oacc[nt][r] * inv[r];
#pragma unroll
    for (int r = 0; r < 4; ++r) qn[r] = __shfl_xor(o[r], 1);
#pragma unroll
    for (int k = 0; k < 2; ++k) {
      const int r = rsel + k;
      f16x2 pv;
      if (lane & 1) {
        pv.x = (_Float16)qn[r];
        pv.y = (_Float16)o[r];
      } else {
        pv.x = (_Float16)o[r];
        pv.y = (_Float16)qn[r];
      }
      const size_t grow = (size_t)b * 2048 + q0 + w4 * 16 + quad * 4 + r;
      const size_t g = ((grow >> 7) * 144 + h * 18 + nt * 2 + (colb >> 3)) * 128 +
                       (grow & 127);
      *(f16x2*)(Out + g * 8 + (colb & 7)) = pv;
    }
  }
}

// ============================================================================
extern "C" void kernel_launch(void* const* d_in, const int* in_sizes, int n_in,
                              void* d_out, int out_size, void* d_ws, size_t ws_size,
                              hipStream_t stream) {
  const float* x = (const float*)d_in[0];
  const float* wq = (const float*)d_in[1];
  const float* bq = (const float*)d_in[2];
  const float* wkv = (const float*)d_in[3];
  const float* bkv = (const float*)d_in[4];
  const float* wo = (const float*)d_in[5];
  const float* bo = (const float*)d_in[6];
  const float* fc = (const float*)d_in[7];
  const float* fs = (const float*)d_in[8];
  // d_in[9..12] (k_cache, v_cache, mask, start_pos) unused: start_pos=0 prefill.
  float* out = (float*)d_out;
  char* ws = (char*)d_ws;

  _Float16* x_sw = (_Float16*)(ws + 0);
  _Float16* wqkv_sw = (_Float16*)(ws + 18874368);
  _Float16* wo_sw = (_Float16*)(ws + 23003136);
  float* bias_qkv = (float*)(ws + 25657344);
  float* qkv = (float*)(ws + 25664256);
  _Float16* Qh = (_Float16*)(ws + 82287360);
  _Float16* Ksw = (_Float16*)(ws + 101161728);
  _Float16* Vsw = (_Float16*)(ws + 105880320);
  _Float16* attn_sw = (_Float16*)(ws + 110598912);

  // swizzled f16 casts (KC = 1152/8 = 144 granules/row; nG = blocks*144*128)
  cvt_sw<<<4608, THREADS, 0, stream>>>(x, x_sw, 1179648, 144, 8192);
  cvt_sw<<<648, THREADS, 0, stream>>>(wq, wqkv_sw, 165888, 144, 1152);
  cvt_sw<<<360, THREADS, 0, stream>>>(wkv, wqkv_sw + 1327104, 92160, 144, 576);
  cvt_sw<<<648, THREADS, 0, stream>>>(wo, wo_sw, 165888, 144, 1152);
  prep_bias<<<7, THREADS, 0, stream>>>(bq, bkv, bias_qkv);

  gemm_sw<<<dim3(14, 64), THREADS, 0, stream>>>(x_sw, wqkv_sw, bias_qkv, qkv,
                                                8192, 1728, 1152);

  rope_scatter_f16<<<23040, THREADS, 0, stream>>>(qkv, fc, fs, Qh, Ksw);
  v_transpose<<<dim3(16, 2, 4), THREADS, 0, stream>>>(qkv, Vsw);

  attn_mfma<<<dim3(32, 4, 4), 512, 0, stream>>>(Qh, Ksw, Vsw, attn_sw);

  gemm_sw<<<dim3(9, 64), THREADS, 0, stream>>>(attn_sw, wo_sw, bo, out, 8192,
                                               1152, 1152);
}